// Round 2
// baseline (324.717 us; speedup 1.0000x reference)
//
#include <hip/hip_runtime.h>
#include <hip/hip_bf16.h>

typedef unsigned short u16;
typedef __attribute__((ext_vector_type(8))) short bf16x8;  // 8 bf16 (4 VGPRs)
typedef __attribute__((ext_vector_type(4))) short bf16x4;  // 4 bf16 (2 VGPRs)
typedef __attribute__((ext_vector_type(4))) float f32x4;

#define DEVI __device__ __forceinline__

DEVI u16 f2bf(float f) {
  union { float f; unsigned int u; } v; v.f = f;
  unsigned int u = v.u;
  unsigned int r = (u + 0x7fffu + ((u >> 16) & 1u)) >> 16;  // RNE
  return (u16)r;
}

DEVI f32x4 mfma16x16x16_bf16(bf16x4 a, bf16x4 b, f32x4 c) {
#if __has_builtin(__builtin_amdgcn_mfma_f32_16x16x16bf16_1k)
  return __builtin_amdgcn_mfma_f32_16x16x16bf16_1k(a, b, c, 0, 0, 0);
#else
  f32x4 d;
  asm volatile("v_mfma_f32_16x16x16_bf16 %0, %1, %2, %3"
               : "=v"(d) : "v"(a), "v"(b), "v"(c));
  return d;
#endif
}

// ---------------- fp32 -> bf16 conversion ----------------
__global__ __launch_bounds__(256) void cvt_kernel(const float4* __restrict__ in,
                                                  u16* __restrict__ out, int n4) {
  int i = blockIdx.x * 256 + threadIdx.x;
  if (i < n4) {
    float4 f = in[i];
    ushort4 o;
    o.x = f2bf(f.x); o.y = f2bf(f.y); o.z = f2bf(f.z); o.w = f2bf(f.w);
    ((ushort4*)out)[i] = o;
  }
}

// ---------------- in_proj GEMM: qvk = x @ w_in^T + b_in ----------------
// M=4096 (B*S), K=512, N=1536. chunk order quirk: cols 0..511 -> Q,
// 512..1023 -> V, 1024..1535 -> K. Q,K as [bh][S][64]; V transposed [bh][64][S].
__global__ __launch_bounds__(256) void inproj_gemm(
    const u16* __restrict__ xb, const u16* __restrict__ wb,
    const float* __restrict__ bin,
    u16* __restrict__ Qb, u16* __restrict__ Kb, u16* __restrict__ Vt) {
  const int K = 512;
  int wave = threadIdx.x >> 6;
  int lane = threadIdx.x & 63;
  int ql = lane & 15, quad = lane >> 4;
  int mbase = blockIdx.x * 64 + wave * 16;
  int nbase = blockIdx.y * 64;

  f32x4 acc[4] = {{0,0,0,0},{0,0,0,0},{0,0,0,0},{0,0,0,0}};
  const u16* ap  = xb + (mbase + ql) * K + quad * 8;
  const u16* bp0 = wb + (nbase +      ql) * K + quad * 8;
  const u16* bp1 = wb + (nbase + 16 + ql) * K + quad * 8;
  const u16* bp2 = wb + (nbase + 32 + ql) * K + quad * 8;
  const u16* bp3 = wb + (nbase + 48 + ql) * K + quad * 8;
#pragma unroll 4
  for (int k0 = 0; k0 < K; k0 += 32) {
    bf16x8 a  = *(const bf16x8*)(ap + k0);
    bf16x8 b0 = *(const bf16x8*)(bp0 + k0);
    bf16x8 b1 = *(const bf16x8*)(bp1 + k0);
    bf16x8 b2 = *(const bf16x8*)(bp2 + k0);
    bf16x8 b3 = *(const bf16x8*)(bp3 + k0);
    acc[0] = __builtin_amdgcn_mfma_f32_16x16x32_bf16(a, b0, acc[0], 0, 0, 0);
    acc[1] = __builtin_amdgcn_mfma_f32_16x16x32_bf16(a, b1, acc[1], 0, 0, 0);
    acc[2] = __builtin_amdgcn_mfma_f32_16x16x32_bf16(a, b2, acc[2], 0, 0, 0);
    acc[3] = __builtin_amdgcn_mfma_f32_16x16x32_bf16(a, b3, acc[3], 0, 0, 0);
  }
#pragma unroll
  for (int t = 0; t < 4; ++t) {
    int n = nbase + t * 16 + ql;
    float bias = bin[n];
    int chunk = n >> 9;       // 0=q, 1=v, 2=k
    int nc = n & 511;
    int h = nc >> 6, d = nc & 63;
#pragma unroll
    for (int r = 0; r < 4; ++r) {
      int m = mbase + quad * 4 + r;    // C/D row = quad*4+reg
      int b = m >> 11, s = m & 2047;
      u16 val = f2bf(acc[t][r] + bias);
      int bh = b * 8 + h;
      if (chunk == 0)      Qb[(bh * 2048 + s) * 64 + d] = val;
      else if (chunk == 2) Kb[(bh * 2048 + s) * 64 + d] = val;
      else                 Vt[(bh * 64 + d) * 2048 + s] = val;
    }
  }
}

// ---------------- flash attention (causal), register-only P ----------------
// One wave (64 thr) per 16-row q-tile. Scores computed TRANSPOSED:
// S^T = K_tile x Q  (A=K, B=Q), so D layout (key=quad*4+r, q=lane&15) is
// exactly the B-operand layout of mfma_f32_16x16x16_bf16 -> P^T feeds
// O^T = V^T x P^T straight from registers. No LDS anywhere.
// Grid x reversed: longest q-tiles dispatched first (causal load balance).
__global__ __launch_bounds__(64) void attn_kernel(
    const u16* __restrict__ Qb, const u16* __restrict__ Kb,
    const u16* __restrict__ Vt, u16* __restrict__ Ob) {
  const int S = 2048;
  int lane = threadIdx.x;
  int ql = lane & 15, quad = lane >> 4;
  int qt = 127 - blockIdx.x;     // longest first
  int bh = blockIdx.y;
  int qbase = qt * 16;
  int q = qbase + ql;
  const u16* Qh = Qb + bh * S * 64;
  const u16* Kh = Kb + bh * S * 64;
  const u16* Vh = Vt + bh * 64 * S;

  bf16x8 q0 = *(const bf16x8*)(Qh + q * 64 + quad * 8);        // dh 0..31
  bf16x8 q1 = *(const bf16x8*)(Qh + q * 64 + 32 + quad * 8);   // dh 32..63

  f32x4 o[4] = {{0,0,0,0},{0,0,0,0},{0,0,0,0},{0,0,0,0}};  // O^T[d=t*16+quad*4+r][q=ql]
  float m = -3.0e38f, l = 0.0f;

  int nkb = (qbase + 15) / 64 + 1;   // 64-key blocks
  for (int kb = 0; kb < nkb; ++kb) {
    int kbase = kb * 64;
    // --- QK^T (transposed): 4 tiles of 16 keys ---
    f32x4 st[4];
#pragma unroll
    for (int t = 0; t < 4; ++t) {
      const u16* kp = Kh + (kbase + t * 16 + ql) * 64 + quad * 8;
      f32x4 s = {0, 0, 0, 0};
      s = __builtin_amdgcn_mfma_f32_16x16x32_bf16(*(const bf16x8*)(kp),      q0, s, 0, 0, 0);
      s = __builtin_amdgcn_mfma_f32_16x16x32_bf16(*(const bf16x8*)(kp + 32), q1, s, 0, 0, 0);
      st[t] = s;
    }
    // --- scale + causal mask ---
    bool needmask = (kbase + 63 > qbase);
    float sc[4][4];
#pragma unroll
    for (int t = 0; t < 4; ++t) {
#pragma unroll
      for (int r = 0; r < 4; ++r) {
        float v = st[t][r] * 0.125f;   // 1/sqrt(64)
        if (needmask) {
          int key = kbase + t * 16 + quad * 4 + r;
          if (key > q) v = -3.0e38f;
        }
        sc[t][r] = v;
      }
    }
    // --- online softmax: in-lane reduce (16 vals) + 2 shuffle rounds over quads ---
    float mx = sc[0][0];
#pragma unroll
    for (int t = 0; t < 4; ++t)
#pragma unroll
      for (int r = 0; r < 4; ++r) mx = fmaxf(mx, sc[t][r]);
    mx = fmaxf(mx, __shfl_xor(mx, 16));
    mx = fmaxf(mx, __shfl_xor(mx, 32));
    float mn = fmaxf(m, mx);
    float alpha = __expf(m - mn);      // 0 on first block
    m = mn;
    float rs = 0.0f;
    bf16x4 p[4];
#pragma unroll
    for (int t = 0; t < 4; ++t) {
#pragma unroll
      for (int r = 0; r < 4; ++r) {
        float e = __expf(sc[t][r] - mn);
        rs += e;
        p[t][r] = (short)f2bf(e);      // P^T[key=quad*4+r (in tile t)][q=ql]
      }
    }
    rs += __shfl_xor(rs, 16);
    rs += __shfl_xor(rs, 32);
    l = l * alpha + rs;
#pragma unroll
    for (int d = 0; d < 4; ++d) o[d] *= alpha;
    // --- PV: O^T += V^T x P^T, 16x16x16 MFMA, P straight from registers ---
#pragma unroll
    for (int t = 0; t < 4; ++t) {
#pragma unroll
      for (int d = 0; d < 4; ++d) {
        bf16x4 vf = *(const bf16x4*)(Vh + (d * 16 + ql) * S + kbase + t * 16 + quad * 4);
        o[d] = mfma16x16x16_bf16(vf, p[t], o[d]);
      }
    }
  }
  // --- epilogue: O^T -> Ob[B*S][512] bf16, head-interleaved columns ---
  float inv = 1.0f / l;
  int b = bh >> 3, h = bh & 7;
  size_t row = (size_t)(b * 2048 + q) * 512 + h * 64;
#pragma unroll
  for (int d = 0; d < 4; ++d) {
    ushort4 v;
    v.x = f2bf(o[d][0] * inv);
    v.y = f2bf(o[d][1] * inv);
    v.z = f2bf(o[d][2] * inv);
    v.w = f2bf(o[d][3] * inv);
    *(ushort4*)(Ob + row + d * 16 + quad * 4) = v;
  }
}

// ---------------- out_proj GEMM: out = O @ w_out^T + b_out (fp32 out) ----------------
__global__ __launch_bounds__(256) void outproj_gemm(
    const u16* __restrict__ Ob, const u16* __restrict__ wb,
    const float* __restrict__ bout, float* __restrict__ out) {
  const int K = 512;
  int wave = threadIdx.x >> 6;
  int lane = threadIdx.x & 63;
  int ql = lane & 15, quad = lane >> 4;
  int mbase = blockIdx.x * 64 + wave * 16;
  int nbase = blockIdx.y * 64;

  f32x4 acc[4] = {{0,0,0,0},{0,0,0,0},{0,0,0,0},{0,0,0,0}};
  const u16* ap  = Ob + (mbase + ql) * K + quad * 8;
  const u16* bp0 = wb + (nbase +      ql) * K + quad * 8;
  const u16* bp1 = wb + (nbase + 16 + ql) * K + quad * 8;
  const u16* bp2 = wb + (nbase + 32 + ql) * K + quad * 8;
  const u16* bp3 = wb + (nbase + 48 + ql) * K + quad * 8;
#pragma unroll 4
  for (int k0 = 0; k0 < K; k0 += 32) {
    bf16x8 a  = *(const bf16x8*)(ap + k0);
    bf16x8 b0 = *(const bf16x8*)(bp0 + k0);
    bf16x8 b1 = *(const bf16x8*)(bp1 + k0);
    bf16x8 b2 = *(const bf16x8*)(bp2 + k0);
    bf16x8 b3 = *(const bf16x8*)(bp3 + k0);
    acc[0] = __builtin_amdgcn_mfma_f32_16x16x32_bf16(a, b0, acc[0], 0, 0, 0);
    acc[1] = __builtin_amdgcn_mfma_f32_16x16x32_bf16(a, b1, acc[1], 0, 0, 0);
    acc[2] = __builtin_amdgcn_mfma_f32_16x16x32_bf16(a, b2, acc[2], 0, 0, 0);
    acc[3] = __builtin_amdgcn_mfma_f32_16x16x32_bf16(a, b3, acc[3], 0, 0, 0);
  }
#pragma unroll
  for (int t = 0; t < 4; ++t) {
    int n = nbase + t * 16 + ql;
    float bias = bout[n];
#pragma unroll
    for (int r = 0; r < 4; ++r) {
      int m = mbase + quad * 4 + r;
      out[m * 512 + n] = acc[t][r] + bias;
    }
  }
}

extern "C" void kernel_launch(void* const* d_in, const int* in_sizes, int n_in,
                              void* d_out, int out_size, void* d_ws, size_t ws_size,
                              hipStream_t stream) {
  const float* x     = (const float*)d_in[0];  // [2,2048,512]
  const float* w_in  = (const float*)d_in[1];  // [1536,512]
  const float* b_in  = (const float*)d_in[2];  // [1536]
  const float* w_out = (const float*)d_in[3];  // [512,512]
  const float* b_out = (const float*)d_in[4];  // [512]
  float* out = (float*)d_out;                  // [2,2048,512] fp32
  char* ws = (char*)d_ws;

  // ws layout (bytes), all 16B-aligned
  u16* xb    = (u16*)(ws);             // 4096x512 bf16   (4 MB)
  u16* winb  = (u16*)(ws + 4194304);   // 1536x512 bf16   (1.5 MB)
  u16* woutb = (u16*)(ws + 5767168);   // 512x512 bf16    (0.5 MB)
  u16* Qb    = (u16*)(ws + 6291456);   // [16][2048][64]  (4 MB)
  u16* Kb    = (u16*)(ws + 10485760);  // [16][2048][64]  (4 MB)
  u16* Vt    = (u16*)(ws + 14680064);  // [16][64][2048]  (4 MB)
  u16* Ob    = (u16*)(ws + 18874368);  // [4096][512]     (4 MB)

  cvt_kernel<<<2048, 256, 0, stream>>>((const float4*)x, xb, 524288);
  cvt_kernel<<<768, 256, 0, stream>>>((const float4*)w_in, winb, 196608);
  cvt_kernel<<<256, 256, 0, stream>>>((const float4*)w_out, woutb, 65536);
  inproj_gemm<<<dim3(64, 24), 256, 0, stream>>>(xb, winb, b_in, Qb, Kb, Vt);
  attn_kernel<<<dim3(128, 16), 64, 0, stream>>>(Qb, Kb, Vt, Ob);
  outproj_gemm<<<dim3(64, 8), 256, 0, stream>>>(Ob, woutb, b_out, out);
}

// Round 3
// 157.450 us; speedup vs baseline: 2.0623x; 2.0623x over previous
//
#include <hip/hip_runtime.h>
#include <hip/hip_bf16.h>

typedef unsigned short u16;
typedef unsigned int u32;
typedef __attribute__((ext_vector_type(8))) short bf16x8;  // 8 bf16 (4 VGPRs)
typedef __attribute__((ext_vector_type(4))) short bf16x4;  // 4 bf16 (2 VGPRs)
typedef __attribute__((ext_vector_type(4))) float f32x4;

#define DEVI __device__ __forceinline__

DEVI u16 f2bf(float f) {
  union { float f; unsigned int u; } v; v.f = f;
  unsigned int u = v.u;
  unsigned int r = (u + 0x7fffu + ((u >> 16) & 1u)) >> 16;  // RNE
  return (u16)r;
}

// async global->LDS, 16B per lane; LDS dest = uniform base + lane*16
DEVI void lds_cp16(u16* lds, const u16* g) {
  __builtin_amdgcn_global_load_lds(
      (const __attribute__((address_space(1))) u32*)g,
      (__attribute__((address_space(3))) u32*)lds, 16, 0, 0);
}

DEVI f32x4 mfma16x16x16_bf16(bf16x4 a, bf16x4 b, f32x4 c) {
#if __has_builtin(__builtin_amdgcn_mfma_f32_16x16x16bf16_1k)
  return __builtin_amdgcn_mfma_f32_16x16x16bf16_1k(a, b, c, 0, 0, 0);
#else
  f32x4 d;
  asm volatile("v_mfma_f32_16x16x16_bf16 %0, %1, %2, %3"
               : "=v"(d) : "v"(a), "v"(b), "v"(c));
  return d;
#endif
}

// ---------------- fp32 -> bf16 conversion (x, w_in, w_out merged) ----------------
__global__ __launch_bounds__(256) void cvt_all(
    const float4* __restrict__ x, const float4* __restrict__ wi,
    const float4* __restrict__ wo, u16* __restrict__ xb,
    u16* __restrict__ wib, u16* __restrict__ wob) {
  int i = blockIdx.x * 256 + threadIdx.x;
  const float4* src; u16* dst; int off;
  if (i < 524288)      { src = x;  dst = xb;  off = i; }
  else if (i < 720896) { src = wi; dst = wib; off = i - 524288; }
  else                 { src = wo; dst = wob; off = i - 720896; }
  float4 f = src[off];
  ushort4 o;
  o.x = f2bf(f.x); o.y = f2bf(f.y); o.z = f2bf(f.z); o.w = f2bf(f.w);
  ((ushort4*)dst)[off] = o;
}

// ---------------- in_proj GEMM: qvk = x @ w_in^T + b_in ----------------
// M=4096, K=512, N=1536, 128x128 tile, BK=32, LDS double-buffered via
// global_load_lds. Rows' 16B chunks XOR-swizzled (c ^= row&3) to kill bank
// conflicts on frag reads. chunk-order quirk: cols 0..511 -> Q, 512..1023 -> V,
// 1024..1535 -> K. Q,K as [bh][S][64]; V transposed [bh][64][S].
__global__ __launch_bounds__(256) void inproj_gemm(
    const u16* __restrict__ xb, const u16* __restrict__ wb,
    const float* __restrict__ bin,
    u16* __restrict__ Qb, u16* __restrict__ Kb, u16* __restrict__ Vt) {
  const int K = 512;
  __shared__ u16 At[2][128 * 32];
  __shared__ u16 Bt[2][128 * 32];
  int tid = threadIdx.x;
  int w = tid >> 6, lane = tid & 63;
  int ql = lane & 15, quad = lane >> 4;
  int wr = w >> 1, wc = w & 1;
  int mtile = blockIdx.x * 128, ntile = blockIdx.y * 128;

  int r4 = lane >> 2, c4 = lane & 3;
  int swz4 = c4 ^ (r4 & 3);   // global 16B-chunk this lane stages

  const u16* ag0 = xb + (size_t)(mtile + w * 32 + r4) * K + swz4 * 8;
  const u16* bg0 = wb + (size_t)(ntile + w * 32 + r4) * K + swz4 * 8;

  f32x4 acc[4][4];
#pragma unroll
  for (int t = 0; t < 4; ++t)
#pragma unroll
    for (int u = 0; u < 4; ++u) acc[t][u] = (f32x4){0, 0, 0, 0};

  // prologue stage k0=0 into buf 0
  lds_cp16(&At[0][w * 1024], ag0);
  lds_cp16(&At[0][w * 1024 + 512], ag0 + 16 * K);
  lds_cp16(&Bt[0][w * 1024], bg0);
  lds_cp16(&Bt[0][w * 1024 + 512], bg0 + 16 * K);

  int cb = ql & 3;
  for (int kk = 0; kk < 16; ++kk) {
    int cur = kk & 1;
    __syncthreads();   // drains staging of cur + prior compute on nxt
    if (kk < 15) {
      int k0 = (kk + 1) * 32;
      lds_cp16(&At[cur ^ 1][w * 1024], ag0 + k0);
      lds_cp16(&At[cur ^ 1][w * 1024 + 512], ag0 + 16 * K + k0);
      lds_cp16(&Bt[cur ^ 1][w * 1024], bg0 + k0);
      lds_cp16(&Bt[cur ^ 1][w * 1024 + 512], bg0 + 16 * K + k0);
    }
    bf16x8 af[4], bf[4];
#pragma unroll
    for (int t = 0; t < 4; ++t) {
      int row = wr * 64 + t * 16 + ql;   // row&3 == ql&3
      af[t] = *(const bf16x8*)(&At[cur][row * 32 + ((quad ^ cb) * 8)]);
    }
#pragma unroll
    for (int u = 0; u < 4; ++u) {
      int row = wc * 64 + u * 16 + ql;
      bf[u] = *(const bf16x8*)(&Bt[cur][row * 32 + ((quad ^ cb) * 8)]);
    }
#pragma unroll
    for (int t = 0; t < 4; ++t)
#pragma unroll
      for (int u = 0; u < 4; ++u)
        acc[t][u] = __builtin_amdgcn_mfma_f32_16x16x32_bf16(af[t], bf[u], acc[t][u], 0, 0, 0);
  }

#pragma unroll
  for (int u = 0; u < 4; ++u) {
    int n = ntile + wc * 64 + u * 16 + ql;
    float bias = bin[n];
    int chunk = n >> 9;       // 0=q, 1=v, 2=k
    int nc = n & 511;
    int h = nc >> 6, d = nc & 63;
#pragma unroll
    for (int t = 0; t < 4; ++t)
#pragma unroll
      for (int r = 0; r < 4; ++r) {
        int m = mtile + wr * 64 + t * 16 + quad * 4 + r;
        int b = m >> 11, s = m & 2047;
        u16 val = f2bf(acc[t][u][r] + bias);
        int bh = b * 8 + h;
        if (chunk == 0)      Qb[((size_t)bh * 2048 + s) * 64 + d] = val;
        else if (chunk == 2) Kb[((size_t)bh * 2048 + s) * 64 + d] = val;
        else                 Vt[((size_t)bh * 64 + d) * 2048 + s] = val;
      }
  }
}

// ---------------- flash attention (causal) ----------------
// Workgroup = 4 waves = 64 q-rows (one tile); k-blocks of 64 staged in LDS
// (K 8KB + V^T 8KB, double-buffered, XOR-swizzled c^=row&7), shared by all
// 4 waves. All waves have identical trip count (tile+1) -> __syncthreads OK.
// Scores computed transposed (S^T = K x Q) so P^T feeds O^T = V^T x P^T
// straight from registers. Longest tiles dispatched first.
__global__ __launch_bounds__(256) void attn_kernel(
    const u16* __restrict__ Qb, const u16* __restrict__ Kb,
    const u16* __restrict__ Vt, u16* __restrict__ Ob) {
  const int S = 2048;
  __shared__ u16 Kt[2][64 * 64];   // [key-row][64 elems, 16B chunks swizzled]
  __shared__ u16 Vl[2][64 * 64];   // [d][64 keys, swizzled]
  int tid = threadIdx.x;
  int w = tid >> 6, lane = tid & 63;
  int ql = lane & 15, quad = lane >> 4;
  int tile = 31 - blockIdx.x;      // longest first
  int bh = blockIdx.y;
  int qbase = tile * 64 + w * 16;
  int q = qbase + ql;
  const u16* Qh = Qb + (size_t)bh * S * 64;
  const u16* Kh = Kb + (size_t)bh * S * 64;
  const u16* Vh = Vt + (size_t)bh * 64 * S;

  int r8 = lane >> 3, c8 = lane & 7;
  int swz = c8 ^ r8;   // global 16B-chunk this lane stages (row&7 == r8)

  bf16x8 q0 = *(const bf16x8*)(Qh + (size_t)q * 64 + quad * 8);       // dh 0..31
  bf16x8 q1 = *(const bf16x8*)(Qh + (size_t)q * 64 + 32 + quad * 8);  // dh 32..63

  f32x4 o[4] = {{0,0,0,0},{0,0,0,0},{0,0,0,0},{0,0,0,0}};  // O^T[d=t16+quad*4+r][q=ql]
  float m = -3.0e38f, l = 0.0f;
  int cb = ql & 7;
  int nkb = tile + 1;

  // prologue: stage k-block 0 into buf 0
  {
    const u16* kg = Kh + (size_t)(w * 16 + r8) * 64 + swz * 8;
    lds_cp16(&Kt[0][w * 1024], kg);
    lds_cp16(&Kt[0][w * 1024 + 512], kg + 8 * 64);
    const u16* vg = Vh + (size_t)(w * 16 + r8) * S + swz * 8;
    lds_cp16(&Vl[0][w * 1024], vg);
    lds_cp16(&Vl[0][w * 1024 + 512], vg + 8 * S);
  }

  for (int kb = 0; kb < nkb; ++kb) {
    int cur = kb & 1;
    int kbase = kb * 64;
    __syncthreads();   // staging of cur complete; nxt buffer free
    if (kb + 1 < nkb) {
      int kn = kbase + 64;
      const u16* kg = Kh + (size_t)(kn + w * 16 + r8) * 64 + swz * 8;
      lds_cp16(&Kt[cur ^ 1][w * 1024], kg);
      lds_cp16(&Kt[cur ^ 1][w * 1024 + 512], kg + 8 * 64);
      const u16* vg = Vh + (size_t)(w * 16 + r8) * S + kn + swz * 8;
      lds_cp16(&Vl[cur ^ 1][w * 1024], vg);
      lds_cp16(&Vl[cur ^ 1][w * 1024 + 512], vg + 8 * S);
    }
    // --- S^T = K x Q, 4 tiles of 16 keys ---
    f32x4 st[4];
#pragma unroll
    for (int t = 0; t < 4; ++t) {
      const u16* kr = &Kt[cur][(t * 16 + ql) * 64];
      bf16x8 kf0 = *(const bf16x8*)(kr + ((quad ^ cb) * 8));        // k 0..31 chunk
      bf16x8 kf1 = *(const bf16x8*)(kr + (((quad + 4) ^ cb) * 8));  // k 32..63
      f32x4 s = {0, 0, 0, 0};
      s = __builtin_amdgcn_mfma_f32_16x16x32_bf16(kf0, q0, s, 0, 0, 0);
      s = __builtin_amdgcn_mfma_f32_16x16x32_bf16(kf1, q1, s, 0, 0, 0);
      st[t] = s;
    }
    // --- scale + causal mask ---
    bool needmask = (kbase + 63 > qbase);
    float sc[4][4];
#pragma unroll
    for (int t = 0; t < 4; ++t)
#pragma unroll
      for (int r = 0; r < 4; ++r) {
        float v = st[t][r] * 0.125f;   // 1/sqrt(64)
        if (needmask) {
          int key = kbase + t * 16 + quad * 4 + r;
          if (key > q) v = -3.0e38f;
        }
        sc[t][r] = v;
      }
    // --- online softmax: in-lane reduce + 2 shuffle rounds ---
    float mx = sc[0][0];
#pragma unroll
    for (int t = 0; t < 4; ++t)
#pragma unroll
      for (int r = 0; r < 4; ++r) mx = fmaxf(mx, sc[t][r]);
    mx = fmaxf(mx, __shfl_xor(mx, 16));
    mx = fmaxf(mx, __shfl_xor(mx, 32));
    float mn = fmaxf(m, mx);
    float alpha = __expf(m - mn);      // 0 on first block
    m = mn;
    float rs = 0.0f;
    bf16x4 p[4];
#pragma unroll
    for (int t = 0; t < 4; ++t)
#pragma unroll
      for (int r = 0; r < 4; ++r) {
        float e = __expf(sc[t][r] - mn);
        rs += e;
        p[t][r] = (short)f2bf(e);      // P^T[key=quad*4+r in tile t][q=ql]
      }
    rs += __shfl_xor(rs, 16);
    rs += __shfl_xor(rs, 32);
    l = l * alpha + rs;
#pragma unroll
    for (int d = 0; d < 4; ++d) o[d] *= alpha;
    // --- O^T += V^T x P^T (16x16x16, P from registers, V from LDS) ---
#pragma unroll
    for (int t = 0; t < 4; ++t)
#pragma unroll
      for (int d = 0; d < 4; ++d) {
        const u16* vr = &Vl[cur][(d * 16 + ql) * 64];
        bf16x4 vf = *(const bf16x4*)(vr + (((t * 2 + (quad >> 1)) ^ cb) * 8 + (quad & 1) * 4));
        o[d] = mfma16x16x16_bf16(vf, p[t], o[d]);
      }
  }
  // --- epilogue: O^T -> Ob[B*S][512] bf16, head-major columns ---
  float inv = 1.0f / l;
  int b = bh >> 3, h = bh & 7;
  size_t row = ((size_t)b * 2048 + q) * 512 + h * 64;
#pragma unroll
  for (int d = 0; d < 4; ++d) {
    ushort4 v;
    v.x = f2bf(o[d][0] * inv);
    v.y = f2bf(o[d][1] * inv);
    v.z = f2bf(o[d][2] * inv);
    v.w = f2bf(o[d][3] * inv);
    *(ushort4*)(Ob + row + d * 16 + quad * 4) = v;
  }
}

// ---------------- out_proj GEMM: out = O @ w_out^T + b_out (fp32 out) ----------------
// M=4096, K=512, N=512. 64x128 tile (grid 64x4 = 256 blocks), BK=32.
__global__ __launch_bounds__(256) void outproj_gemm(
    const u16* __restrict__ Ob, const u16* __restrict__ wb,
    const float* __restrict__ bout, float* __restrict__ out) {
  const int K = 512;
  __shared__ u16 At[2][64 * 32];
  __shared__ u16 Bt[2][128 * 32];
  int tid = threadIdx.x;
  int w = tid >> 6, lane = tid & 63;
  int ql = lane & 15, quad = lane >> 4;
  int wr = w >> 1, wc = w & 1;
  int mtile = blockIdx.x * 64, ntile = blockIdx.y * 128;

  int r4 = lane >> 2, c4 = lane & 3;
  int swz4 = c4 ^ (r4 & 3);

  const u16* ag0 = Ob + (size_t)(mtile + w * 16 + r4) * K + swz4 * 8;
  const u16* bg0 = wb + (size_t)(ntile + w * 32 + r4) * K + swz4 * 8;

  f32x4 acc[2][4];
#pragma unroll
  for (int t = 0; t < 2; ++t)
#pragma unroll
    for (int u = 0; u < 4; ++u) acc[t][u] = (f32x4){0, 0, 0, 0};

  lds_cp16(&At[0][w * 512], ag0);
  lds_cp16(&Bt[0][w * 1024], bg0);
  lds_cp16(&Bt[0][w * 1024 + 512], bg0 + 16 * K);

  int cb = ql & 3;
  for (int kk = 0; kk < 16; ++kk) {
    int cur = kk & 1;
    __syncthreads();
    if (kk < 15) {
      int k0 = (kk + 1) * 32;
      lds_cp16(&At[cur ^ 1][w * 512], ag0 + k0);
      lds_cp16(&Bt[cur ^ 1][w * 1024], bg0 + k0);
      lds_cp16(&Bt[cur ^ 1][w * 1024 + 512], bg0 + 16 * K + k0);
    }
    bf16x8 af[2], bf[4];
#pragma unroll
    for (int t = 0; t < 2; ++t) {
      int row = wr * 32 + t * 16 + ql;
      af[t] = *(const bf16x8*)(&At[cur][row * 32 + ((quad ^ cb) * 8)]);
    }
#pragma unroll
    for (int u = 0; u < 4; ++u) {
      int row = wc * 64 + u * 16 + ql;
      bf[u] = *(const bf16x8*)(&Bt[cur][row * 32 + ((quad ^ cb) * 8)]);
    }
#pragma unroll
    for (int t = 0; t < 2; ++t)
#pragma unroll
      for (int u = 0; u < 4; ++u)
        acc[t][u] = __builtin_amdgcn_mfma_f32_16x16x32_bf16(af[t], bf[u], acc[t][u], 0, 0, 0);
  }

#pragma unroll
  for (int u = 0; u < 4; ++u) {
    int n = ntile + wc * 64 + u * 16 + ql;
    float bias = bout[n];
#pragma unroll
    for (int t = 0; t < 2; ++t)
#pragma unroll
      for (int r = 0; r < 4; ++r) {
        int mm = mtile + wr * 32 + t * 16 + quad * 4 + r;
        out[(size_t)mm * 512 + n] = acc[t][u][r] + bias;
      }
  }
}

extern "C" void kernel_launch(void* const* d_in, const int* in_sizes, int n_in,
                              void* d_out, int out_size, void* d_ws, size_t ws_size,
                              hipStream_t stream) {
  const float* x     = (const float*)d_in[0];  // [2,2048,512]
  const float* w_in  = (const float*)d_in[1];  // [1536,512]
  const float* b_in  = (const float*)d_in[2];  // [1536]
  const float* w_out = (const float*)d_in[3];  // [512,512]
  const float* b_out = (const float*)d_in[4];  // [512]
  float* out = (float*)d_out;                  // [2,2048,512] fp32
  char* ws = (char*)d_ws;

  u16* xb    = (u16*)(ws);             // 4096x512 bf16   (4 MB)
  u16* winb  = (u16*)(ws + 4194304);   // 1536x512 bf16   (1.5 MB)
  u16* woutb = (u16*)(ws + 5767168);   // 512x512 bf16    (0.5 MB)
  u16* Qb    = (u16*)(ws + 6291456);   // [16][2048][64]  (4 MB)
  u16* Kb    = (u16*)(ws + 10485760);  // [16][2048][64]  (4 MB)
  u16* Vt    = (u16*)(ws + 14680064);  // [16][64][2048]  (4 MB)
  u16* Ob    = (u16*)(ws + 18874368);  // [4096][512]     (4 MB)

  cvt_all<<<3072, 256, 0, stream>>>((const float4*)x, (const float4*)w_in,
                                    (const float4*)w_out, xb, winb, woutb);
  inproj_gemm<<<dim3(32, 12), 256, 0, stream>>>(xb, winb, b_in, Qb, Kb, Vt);
  attn_kernel<<<dim3(32, 16), 256, 0, stream>>>(Qb, Kb, Vt, Ob);
  outproj_gemm<<<dim3(64, 4), 256, 0, stream>>>(Ob, woutb, b_out, out);
}

// Round 4
// 141.744 us; speedup vs baseline: 2.2909x; 1.1108x over previous
//
#include <hip/hip_runtime.h>
#include <hip/hip_bf16.h>

typedef unsigned short u16;
typedef unsigned int u32;
typedef __attribute__((ext_vector_type(8))) short bf16x8;  // 8 bf16 (4 VGPRs)
typedef __attribute__((ext_vector_type(4))) short bf16x4;  // 4 bf16 (2 VGPRs)
typedef __attribute__((ext_vector_type(4))) float f32x4;

#define DEVI __device__ __forceinline__

DEVI u16 f2bf(float f) {
  union { float f; unsigned int u; } v; v.f = f;
  unsigned int u = v.u;
  unsigned int r = (u + 0x7fffu + ((u >> 16) & 1u)) >> 16;  // RNE
  return (u16)r;
}

DEVI float fexp2(float x) {
#if __has_builtin(__builtin_amdgcn_exp2f)
  return __builtin_amdgcn_exp2f(x);
#else
  return exp2f(x);
#endif
}

// async global->LDS, 16B per lane; LDS dest = uniform base + lane*16
DEVI void lds_cp16(u16* lds, const u16* g) {
  __builtin_amdgcn_global_load_lds(
      (const __attribute__((address_space(1))) u32*)g,
      (__attribute__((address_space(3))) u32*)lds, 16, 0, 0);
}

DEVI f32x4 mfma16x16x16_bf16(bf16x4 a, bf16x4 b, f32x4 c) {
#if __has_builtin(__builtin_amdgcn_mfma_f32_16x16x16bf16_1k)
  return __builtin_amdgcn_mfma_f32_16x16x16bf16_1k(a, b, c, 0, 0, 0);
#else
  f32x4 d;
  asm volatile("v_mfma_f32_16x16x16_bf16 %0, %1, %2, %3"
               : "=v"(d) : "v"(a), "v"(b), "v"(c));
  return d;
#endif
}

// ---------------- fp32 -> bf16 conversion (x, w_in, w_out merged) ----------------
__global__ __launch_bounds__(256) void cvt_all(
    const float4* __restrict__ x, const float4* __restrict__ wi,
    const float4* __restrict__ wo, u16* __restrict__ xb,
    u16* __restrict__ wib, u16* __restrict__ wob) {
  int i = blockIdx.x * 256 + threadIdx.x;
  const float4* src; u16* dst; int off;
  if (i < 524288)      { src = x;  dst = xb;  off = i; }
  else if (i < 720896) { src = wi; dst = wib; off = i - 524288; }
  else                 { src = wo; dst = wob; off = i - 720896; }
  float4 f = src[off];
  ushort4 o;
  o.x = f2bf(f.x); o.y = f2bf(f.y); o.z = f2bf(f.z); o.w = f2bf(f.w);
  ((ushort4*)dst)[off] = o;
}

// ---------------- in_proj GEMM: qvk = x @ w_in^T + b_in ----------------
// M=4096, K=512, N=1536, 128x128 tile, BK=32, LDS dbuf via global_load_lds.
// chunk-order quirk: cols 0..511 -> Q, 512..1023 -> V, 1024..1535 -> K.
// All three outputs written row-major [bh][s][64] (coalesced); V transposed later.
__global__ __launch_bounds__(256) void inproj_gemm(
    const u16* __restrict__ xb, const u16* __restrict__ wb,
    const float* __restrict__ bin,
    u16* __restrict__ Qb, u16* __restrict__ Kb, u16* __restrict__ Vrow) {
  const int K = 512;
  __shared__ u16 At[2][128 * 32];
  __shared__ u16 Bt[2][128 * 32];
  int tid = threadIdx.x;
  int w = tid >> 6, lane = tid & 63;
  int ql = lane & 15, quad = lane >> 4;
  int wr = w >> 1, wc = w & 1;
  int mtile = blockIdx.x * 128, ntile = blockIdx.y * 128;

  int r4 = lane >> 2, c4 = lane & 3;
  int swz4 = c4 ^ (r4 & 3);   // global 16B-chunk this lane stages

  const u16* ag0 = xb + (size_t)(mtile + w * 32 + r4) * K + swz4 * 8;
  const u16* bg0 = wb + (size_t)(ntile + w * 32 + r4) * K + swz4 * 8;

  f32x4 acc[4][4];
#pragma unroll
  for (int t = 0; t < 4; ++t)
#pragma unroll
    for (int u = 0; u < 4; ++u) acc[t][u] = (f32x4){0, 0, 0, 0};

  lds_cp16(&At[0][w * 1024], ag0);
  lds_cp16(&At[0][w * 1024 + 512], ag0 + 16 * K);
  lds_cp16(&Bt[0][w * 1024], bg0);
  lds_cp16(&Bt[0][w * 1024 + 512], bg0 + 16 * K);

  int cb = ql & 3;
  for (int kk = 0; kk < 16; ++kk) {
    int cur = kk & 1;
    __syncthreads();
    if (kk < 15) {
      int k0 = (kk + 1) * 32;
      lds_cp16(&At[cur ^ 1][w * 1024], ag0 + k0);
      lds_cp16(&At[cur ^ 1][w * 1024 + 512], ag0 + 16 * K + k0);
      lds_cp16(&Bt[cur ^ 1][w * 1024], bg0 + k0);
      lds_cp16(&Bt[cur ^ 1][w * 1024 + 512], bg0 + 16 * K + k0);
    }
    bf16x8 af[4], bf[4];
#pragma unroll
    for (int t = 0; t < 4; ++t) {
      int row = wr * 64 + t * 16 + ql;
      af[t] = *(const bf16x8*)(&At[cur][row * 32 + ((quad ^ cb) * 8)]);
    }
#pragma unroll
    for (int u = 0; u < 4; ++u) {
      int row = wc * 64 + u * 16 + ql;
      bf[u] = *(const bf16x8*)(&Bt[cur][row * 32 + ((quad ^ cb) * 8)]);
    }
#pragma unroll
    for (int t = 0; t < 4; ++t)
#pragma unroll
      for (int u = 0; u < 4; ++u)
        acc[t][u] = __builtin_amdgcn_mfma_f32_16x16x32_bf16(af[t], bf[u], acc[t][u], 0, 0, 0);
  }

#pragma unroll
  for (int u = 0; u < 4; ++u) {
    int n = ntile + wc * 64 + u * 16 + ql;
    float bias = bin[n];
    int chunk = n >> 9;       // 0=q, 1=v, 2=k
    int nc = n & 511;
    int h = nc >> 6, d = nc & 63;
#pragma unroll
    for (int t = 0; t < 4; ++t)
#pragma unroll
      for (int r = 0; r < 4; ++r) {
        int m = mtile + wr * 64 + t * 16 + quad * 4 + r;
        int b = m >> 11, s = m & 2047;
        u16 val = f2bf(acc[t][u][r] + bias);
        size_t idx = (((size_t)(b * 8 + h)) * 2048 + s) * 64 + d;
        if (chunk == 0)      Qb[idx] = val;
        else if (chunk == 2) Kb[idx] = val;
        else                 Vrow[idx] = val;
      }
  }
}

// ---------------- V transpose: Vrow [bh][s][64] -> Vt [bh][64][2048] ----------------
__global__ __launch_bounds__(256) void transpose_v(
    const u16* __restrict__ Vrow, u16* __restrict__ Vt) {
  __shared__ u16 T[64][68];   // padded stride to spread banks
  int tid = threadIdx.x;
  int stile = blockIdx.x, bh = blockIdx.y;
  const u16* src = Vrow + ((size_t)bh * 2048 + stile * 64) * 64;
  int r = tid >> 3, c = (tid & 7) * 8;
  *(bf16x8*)&T[r][c]      = *(const bf16x8*)(src + r * 64 + c);
  *(bf16x8*)&T[r + 32][c] = *(const bf16x8*)(src + (r + 32) * 64 + c);
  __syncthreads();
  u16* dst = Vt + (size_t)bh * 64 * 2048 + stile * 64;
#pragma unroll
  for (int p = 0; p < 2; ++p) {
    int oc = p * 256 + tid;
    int d = oc >> 3, sc = (oc & 7) * 8;
    union { bf16x8 v; u16 e[8]; } out;
#pragma unroll
    for (int i = 0; i < 8; ++i) out.e[i] = T[sc + i][d];
    *(bf16x8*)(dst + (size_t)d * 2048 + sc) = out.v;
  }
}

// ---------------- flash attention (causal), within-WG split-K ----------------
// 512 threads = 8 waves = 2 groups of 4. WG owns 64 q-rows (wave -> 16 rows,
// identical in both groups). Group 0 takes k-blocks [0, half), group 1 takes
// [half, tile]; trip counts padded equal so WG-wide __syncthreads is legal
// (dummy iterations skip staging/compute only). Each group has its own
// double-buffered K/V LDS (64 KB total -> 2 WGs/CU, 16 waves/CU). Scores
// transposed (S^T = K x Q) so P^T feeds O^T = V^T x P^T from registers.
// Softmax in exp2 domain. Final (O,m,l) merge via LDS. Longest tiles first.
__global__ __launch_bounds__(512) void attn_kernel(
    const u16* __restrict__ Qb, const u16* __restrict__ Kb,
    const u16* __restrict__ Vt, u16* __restrict__ Ob) {
  const int S = 2048;
  __shared__ u16 Kt[2][2][4096];   // [group][buf][64 keys x 64 dh]
  __shared__ u16 Vl[2][2][4096];   // [group][buf][64 dh x 64 keys]
  int tid = threadIdx.x;
  int grp = tid >> 8;
  int w = (tid >> 6) & 3;          // wave-in-group
  int lane = tid & 63;
  int ql = lane & 15, quad = lane >> 4;
  int tile = 31 - blockIdx.x;      // longest first
  int bh = blockIdx.y;
  int qbase = tile * 64 + w * 16;
  int q = qbase + ql;
  const u16* Qh = Qb + (size_t)bh * S * 64;
  const u16* Kh = Kb + (size_t)bh * S * 64;
  const u16* Vh = Vt + (size_t)bh * 64 * S;

  int r8 = lane >> 3, c8 = lane & 7;
  int swz = c8 ^ r8;
  int cb = ql & 7;
  const float SCL = 0.180336878f;  // (1/sqrt(64)) * log2(e)

  bf16x8 q0 = *(const bf16x8*)(Qh + (size_t)q * 64 + quad * 8);
  bf16x8 q1 = *(const bf16x8*)(Qh + (size_t)q * 64 + 32 + quad * 8);

  f32x4 o[4] = {{0,0,0,0},{0,0,0,0},{0,0,0,0},{0,0,0,0}};
  float m = -3.0e38f, l = 0.0f;
  int half = (tile + 2) >> 1;      // ceil((tile+1)/2)

  // prologue: stage my group's first block
  {
    int kb0 = grp * half;
    if (kb0 <= tile) {
      int kbase = kb0 * 64;
      const u16* kg = Kh + (size_t)(kbase + w * 16 + r8) * 64 + swz * 8;
      lds_cp16(&Kt[grp][0][w * 1024], kg);
      lds_cp16(&Kt[grp][0][w * 1024 + 512], kg + 8 * 64);
      const u16* vg = Vh + (size_t)(w * 16 + r8) * S + kbase + swz * 8;
      lds_cp16(&Vl[grp][0][w * 1024], vg);
      lds_cp16(&Vl[grp][0][w * 1024 + 512], vg + 8 * S);
    }
  }

  for (int j = 0; j < half; ++j) {
    int cur = j & 1;
    int kb = grp * half + j;
    bool real = (kb <= tile);
    int kbase = kb * 64;
    __syncthreads();   // staging of cur drained; nxt buffer free
    {
      int kbn = kb + 1;
      if (j + 1 < half && kbn <= tile) {
        int kn = kbn * 64;
        const u16* kg = Kh + (size_t)(kn + w * 16 + r8) * 64 + swz * 8;
        lds_cp16(&Kt[grp][cur ^ 1][w * 1024], kg);
        lds_cp16(&Kt[grp][cur ^ 1][w * 1024 + 512], kg + 8 * 64);
        const u16* vg = Vh + (size_t)(w * 16 + r8) * S + kn + swz * 8;
        lds_cp16(&Vl[grp][cur ^ 1][w * 1024], vg);
        lds_cp16(&Vl[grp][cur ^ 1][w * 1024 + 512], vg + 8 * S);
      }
    }
    if (!real) continue;
    // --- S^T = K x Q ---
    f32x4 st[4];
#pragma unroll
    for (int t = 0; t < 4; ++t) {
      const u16* kr = &Kt[grp][cur][(t * 16 + ql) * 64];
      bf16x8 kf0 = *(const bf16x8*)(kr + ((quad ^ cb) * 8));
      bf16x8 kf1 = *(const bf16x8*)(kr + (((quad + 4) ^ cb) * 8));
      f32x4 s = {0, 0, 0, 0};
      s = __builtin_amdgcn_mfma_f32_16x16x32_bf16(kf0, q0, s, 0, 0, 0);
      s = __builtin_amdgcn_mfma_f32_16x16x32_bf16(kf1, q1, s, 0, 0, 0);
      st[t] = s;
    }
    // --- scale (exp2 domain) + causal mask ---
    bool needmask = (kbase + 63 > qbase);
    float sc[4][4];
#pragma unroll
    for (int t = 0; t < 4; ++t)
#pragma unroll
      for (int r = 0; r < 4; ++r) {
        float v = st[t][r] * SCL;
        if (needmask) {
          int key = kbase + t * 16 + quad * 4 + r;
          if (key > q) v = -3.0e38f;
        }
        sc[t][r] = v;
      }
    // --- online softmax ---
    float mx = sc[0][0];
#pragma unroll
    for (int t = 0; t < 4; ++t)
#pragma unroll
      for (int r = 0; r < 4; ++r) mx = fmaxf(mx, sc[t][r]);
    mx = fmaxf(mx, __shfl_xor(mx, 16));
    mx = fmaxf(mx, __shfl_xor(mx, 32));
    float mn = fmaxf(m, mx);
    float alpha = fexp2(m - mn);
    m = mn;
    float rs = 0.0f;
    bf16x4 p[4];
#pragma unroll
    for (int t = 0; t < 4; ++t)
#pragma unroll
      for (int r = 0; r < 4; ++r) {
        float e = fexp2(sc[t][r] - mn);
        rs += e;
        p[t][r] = (short)f2bf(e);
      }
    rs += __shfl_xor(rs, 16);
    rs += __shfl_xor(rs, 32);
    l = l * alpha + rs;
#pragma unroll
    for (int d = 0; d < 4; ++d) o[d] *= alpha;
    // --- O^T += V^T x P^T ---
#pragma unroll
    for (int t = 0; t < 4; ++t)
#pragma unroll
      for (int d = 0; d < 4; ++d) {
        const u16* vr = &Vl[grp][cur][(d * 16 + ql) * 64];
        bf16x4 vf = *(const bf16x4*)(vr + (((t * 2 + (quad >> 1)) ^ cb) * 8 + (quad & 1) * 4));
        o[d] = mfma16x16x16_bf16(vf, p[t], o[d]);
      }
  }

  // --- cross-group merge through LDS (K/V buffers are dead now) ---
  float* ob  = (float*)&Kt[0][0][0];   // 256 lanes x 16 floats = 16 KB
  float* mlb = (float*)&Vl[0][0][0];   // 256 lanes x 2 floats
  int lg = tid & 255;
  __syncthreads();
  if (grp == 1) {
#pragma unroll
    for (int d = 0; d < 4; ++d)
#pragma unroll
      for (int r = 0; r < 4; ++r) ob[lg * 16 + d * 4 + r] = o[d][r];
    mlb[lg * 2] = m;
    mlb[lg * 2 + 1] = l;
  }
  __syncthreads();
  if (grp == 0) {
    float mB = mlb[lg * 2], lB = mlb[lg * 2 + 1];
    float M = fmaxf(m, mB);
    float aA = fexp2(m - M), aB = fexp2(mB - M);
    float L = l * aA + lB * aB;
    float inv = 1.0f / L;
    int b = bh >> 3, h = bh & 7;
    size_t row = ((size_t)b * 2048 + q) * 512 + h * 64;
#pragma unroll
    for (int d = 0; d < 4; ++d) {
      ushort4 v;
      v.x = f2bf((o[d][0] * aA + ob[lg * 16 + d * 4 + 0] * aB) * inv);
      v.y = f2bf((o[d][1] * aA + ob[lg * 16 + d * 4 + 1] * aB) * inv);
      v.z = f2bf((o[d][2] * aA + ob[lg * 16 + d * 4 + 2] * aB) * inv);
      v.w = f2bf((o[d][3] * aA + ob[lg * 16 + d * 4 + 3] * aB) * inv);
      *(ushort4*)(Ob + row + d * 16 + quad * 4) = v;
    }
  }
}

// ---------------- out_proj GEMM: out = O @ w_out^T + b_out (fp32 out) ----------------
__global__ __launch_bounds__(256) void outproj_gemm(
    const u16* __restrict__ Ob, const u16* __restrict__ wb,
    const float* __restrict__ bout, float* __restrict__ out) {
  const int K = 512;
  __shared__ u16 At[2][64 * 32];
  __shared__ u16 Bt[2][128 * 32];
  int tid = threadIdx.x;
  int w = tid >> 6, lane = tid & 63;
  int ql = lane & 15, quad = lane >> 4;
  int wr = w >> 1, wc = w & 1;
  int mtile = blockIdx.x * 64, ntile = blockIdx.y * 128;

  int r4 = lane >> 2, c4 = lane & 3;
  int swz4 = c4 ^ (r4 & 3);

  const u16* ag0 = Ob + (size_t)(mtile + w * 16 + r4) * K + swz4 * 8;
  const u16* bg0 = wb + (size_t)(ntile + w * 32 + r4) * K + swz4 * 8;

  f32x4 acc[2][4];
#pragma unroll
  for (int t = 0; t < 2; ++t)
#pragma unroll
    for (int u = 0; u < 4; ++u) acc[t][u] = (f32x4){0, 0, 0, 0};

  lds_cp16(&At[0][w * 512], ag0);
  lds_cp16(&Bt[0][w * 1024], bg0);
  lds_cp16(&Bt[0][w * 1024 + 512], bg0 + 16 * K);

  int cb = ql & 3;
  for (int kk = 0; kk < 16; ++kk) {
    int cur = kk & 1;
    __syncthreads();
    if (kk < 15) {
      int k0 = (kk + 1) * 32;
      lds_cp16(&At[cur ^ 1][w * 512], ag0 + k0);
      lds_cp16(&Bt[cur ^ 1][w * 1024], bg0 + k0);
      lds_cp16(&Bt[cur ^ 1][w * 1024 + 512], bg0 + 16 * K + k0);
    }
    bf16x8 af[2], bf[4];
#pragma unroll
    for (int t = 0; t < 2; ++t) {
      int row = wr * 32 + t * 16 + ql;
      af[t] = *(const bf16x8*)(&At[cur][row * 32 + ((quad ^ cb) * 8)]);
    }
#pragma unroll
    for (int u = 0; u < 4; ++u) {
      int row = wc * 64 + u * 16 + ql;
      bf[u] = *(const bf16x8*)(&Bt[cur][row * 32 + ((quad ^ cb) * 8)]);
    }
#pragma unroll
    for (int t = 0; t < 2; ++t)
#pragma unroll
      for (int u = 0; u < 4; ++u)
        acc[t][u] = __builtin_amdgcn_mfma_f32_16x16x32_bf16(af[t], bf[u], acc[t][u], 0, 0, 0);
  }

#pragma unroll
  for (int u = 0; u < 4; ++u) {
    int n = ntile + wc * 64 + u * 16 + ql;
    float bias = bout[n];
#pragma unroll
    for (int t = 0; t < 2; ++t)
#pragma unroll
      for (int r = 0; r < 4; ++r) {
        int mm = mtile + wr * 32 + t * 16 + quad * 4 + r;
        out[(size_t)mm * 512 + n] = acc[t][u][r] + bias;
      }
  }
}

extern "C" void kernel_launch(void* const* d_in, const int* in_sizes, int n_in,
                              void* d_out, int out_size, void* d_ws, size_t ws_size,
                              hipStream_t stream) {
  const float* x     = (const float*)d_in[0];  // [2,2048,512]
  const float* w_in  = (const float*)d_in[1];  // [1536,512]
  const float* b_in  = (const float*)d_in[2];  // [1536]
  const float* w_out = (const float*)d_in[3];  // [512,512]
  const float* b_out = (const float*)d_in[4];  // [512]
  float* out = (float*)d_out;                  // [2,2048,512] fp32
  char* ws = (char*)d_ws;

  u16* xb    = (u16*)(ws);             // 4096x512 bf16   (4 MB)
  u16* winb  = (u16*)(ws + 4194304);   // 1536x512 bf16   (1.5 MB)
  u16* woutb = (u16*)(ws + 5767168);   // 512x512 bf16    (0.5 MB)
  u16* Qb    = (u16*)(ws + 6291456);   // [16][2048][64]  (4 MB)
  u16* Kb    = (u16*)(ws + 10485760);  // [16][2048][64]  (4 MB)
  u16* Vt    = (u16*)(ws + 14680064);  // [16][64][2048]  (4 MB)
  u16* Ob    = (u16*)(ws + 18874368);  // [4096][512]     (4 MB)
  u16* Vrow  = Ob;   // alias: Vrow dead before attn writes Ob (stream-ordered)

  cvt_all<<<3072, 256, 0, stream>>>((const float4*)x, (const float4*)w_in,
                                    (const float4*)w_out, xb, winb, woutb);
  inproj_gemm<<<dim3(32, 12), 256, 0, stream>>>(xb, winb, b_in, Qb, Kb, Vrow);
  transpose_v<<<dim3(32, 16), 256, 0, stream>>>(Vrow, Vt);
  attn_kernel<<<dim3(32, 16), 512, 0, stream>>>(Qb, Kb, Vt, Ob);
  outproj_gemm<<<dim3(64, 4), 256, 0, stream>>>(Ob, woutb, b_out, out);
}

// Round 5
// 135.531 us; speedup vs baseline: 2.3959x; 1.0458x over previous
//
#include <hip/hip_runtime.h>
#include <hip/hip_bf16.h>

typedef unsigned short u16;
typedef unsigned int u32;
typedef __attribute__((ext_vector_type(8))) short bf16x8;  // 8 bf16 (4 VGPRs)
typedef __attribute__((ext_vector_type(4))) short bf16x4;  // 4 bf16 (2 VGPRs)
typedef __attribute__((ext_vector_type(4))) float f32x4;

#define DEVI __device__ __forceinline__

DEVI u16 f2bf(float f) {
  union { float f; unsigned int u; } v; v.f = f;
  unsigned int u = v.u;
  unsigned int r = (u + 0x7fffu + ((u >> 16) & 1u)) >> 16;  // RNE
  return (u16)r;
}

DEVI float fexp2(float x) {
#if __has_builtin(__builtin_amdgcn_exp2f)
  return __builtin_amdgcn_exp2f(x);
#else
  return exp2f(x);
#endif
}

// async global->LDS, 16B per lane; LDS dest = uniform base + lane*16
DEVI void lds_cp16(u16* lds, const u16* g) {
  __builtin_amdgcn_global_load_lds(
      (const __attribute__((address_space(1))) u32*)g,
      (__attribute__((address_space(3))) u32*)lds, 16, 0, 0);
}

DEVI f32x4 mfma16x16x16_bf16(bf16x4 a, bf16x4 b, f32x4 c) {
#if __has_builtin(__builtin_amdgcn_mfma_f32_16x16x16bf16_1k)
  return __builtin_amdgcn_mfma_f32_16x16x16bf16_1k(a, b, c, 0, 0, 0);
#else
  f32x4 d;
  asm volatile("v_mfma_f32_16x16x16_bf16 %0, %1, %2, %3"
               : "=v"(d) : "v"(a), "v"(b), "v"(c));
  return d;
#endif
}

// ---------------- fp32 -> bf16 conversion (x, w_in, w_out merged) ----------------
__global__ __launch_bounds__(256) void cvt_all(
    const float4* __restrict__ x, const float4* __restrict__ wi,
    const float4* __restrict__ wo, u16* __restrict__ xb,
    u16* __restrict__ wib, u16* __restrict__ wob) {
  int i = blockIdx.x * 256 + threadIdx.x;
  const float4* src; u16* dst; int off;
  if (i < 524288)      { src = x;  dst = xb;  off = i; }
  else if (i < 720896) { src = wi; dst = wib; off = i - 524288; }
  else                 { src = wo; dst = wob; off = i - 720896; }
  float4 f = src[off];
  ushort4 o;
  o.x = f2bf(f.x); o.y = f2bf(f.y); o.z = f2bf(f.z); o.w = f2bf(f.w);
  ((ushort4*)dst)[off] = o;
}

// ---------------- in_proj GEMM: qvk = x @ w_in^T + b_in ----------------
// M=4096, K=512, N=1536. 64x128 tile (grid 64x12 = 768 WGs, ~3/CU), BK=32,
// LDS dbuf via global_load_lds, XOR-swizzled chunks. chunk-order quirk:
// cols 0..511 -> Q, 512..1023 -> V, 1024..1535 -> K. All written row-major
// [bh][s][64] (coalesced); V transposed in a separate pass.
__global__ __launch_bounds__(256) void inproj_gemm(
    const u16* __restrict__ xb, const u16* __restrict__ wb,
    const float* __restrict__ bin,
    u16* __restrict__ Qb, u16* __restrict__ Kb, u16* __restrict__ Vrow) {
  const int K = 512;
  __shared__ u16 At[2][64 * 32];
  __shared__ u16 Bt[2][128 * 32];
  int tid = threadIdx.x;
  int w = tid >> 6, lane = tid & 63;
  int ql = lane & 15, quad = lane >> 4;
  int wr = w >> 1, wc = w & 1;
  int mtile = blockIdx.x * 64, ntile = blockIdx.y * 128;

  int r4 = lane >> 2, c4 = lane & 3;
  int swz4 = c4 ^ (r4 & 3);

  const u16* ag0 = xb + (size_t)(mtile + w * 16 + r4) * K + swz4 * 8;
  const u16* bg0 = wb + (size_t)(ntile + w * 32 + r4) * K + swz4 * 8;

  f32x4 acc[2][4];
#pragma unroll
  for (int t = 0; t < 2; ++t)
#pragma unroll
    for (int u = 0; u < 4; ++u) acc[t][u] = (f32x4){0, 0, 0, 0};

  lds_cp16(&At[0][w * 512], ag0);
  lds_cp16(&Bt[0][w * 1024], bg0);
  lds_cp16(&Bt[0][w * 1024 + 512], bg0 + 16 * K);

  int cb = ql & 3;
  for (int kk = 0; kk < 16; ++kk) {
    int cur = kk & 1;
    __syncthreads();
    if (kk < 15) {
      int k0 = (kk + 1) * 32;
      lds_cp16(&At[cur ^ 1][w * 512], ag0 + k0);
      lds_cp16(&Bt[cur ^ 1][w * 1024], bg0 + k0);
      lds_cp16(&Bt[cur ^ 1][w * 1024 + 512], bg0 + 16 * K + k0);
    }
    bf16x8 af[2], bf[4];
#pragma unroll
    for (int t = 0; t < 2; ++t) {
      int row = wr * 32 + t * 16 + ql;
      af[t] = *(const bf16x8*)(&At[cur][row * 32 + ((quad ^ cb) * 8)]);
    }
#pragma unroll
    for (int u = 0; u < 4; ++u) {
      int row = wc * 64 + u * 16 + ql;
      bf[u] = *(const bf16x8*)(&Bt[cur][row * 32 + ((quad ^ cb) * 8)]);
    }
#pragma unroll
    for (int t = 0; t < 2; ++t)
#pragma unroll
      for (int u = 0; u < 4; ++u)
        acc[t][u] = __builtin_amdgcn_mfma_f32_16x16x32_bf16(af[t], bf[u], acc[t][u], 0, 0, 0);
  }

#pragma unroll
  for (int u = 0; u < 4; ++u) {
    int n = ntile + wc * 64 + u * 16 + ql;
    float bias = bin[n];
    int chunk = n >> 9;       // 0=q, 1=v, 2=k
    int nc = n & 511;
    int h = nc >> 6, d = nc & 63;
#pragma unroll
    for (int t = 0; t < 2; ++t)
#pragma unroll
      for (int r = 0; r < 4; ++r) {
        int m = mtile + wr * 32 + t * 16 + quad * 4 + r;
        int b = m >> 11, s = m & 2047;
        u16 val = f2bf(acc[t][u][r] + bias);
        size_t idx = (((size_t)(b * 8 + h)) * 2048 + s) * 64 + d;
        if (chunk == 0)      Qb[idx] = val;
        else if (chunk == 2) Kb[idx] = val;
        else                 Vrow[idx] = val;
      }
  }
}

// ---------------- V transpose: Vrow [bh][s][64] -> Vt [bh][64][2048] ----------------
__global__ __launch_bounds__(256) void transpose_v(
    const u16* __restrict__ Vrow, u16* __restrict__ Vt) {
  __shared__ u16 T[64][68];
  int tid = threadIdx.x;
  int stile = blockIdx.x, bh = blockIdx.y;
  const u16* src = Vrow + ((size_t)bh * 2048 + stile * 64) * 64;
  int r = tid >> 3, c = (tid & 7) * 8;
  *(bf16x8*)&T[r][c]      = *(const bf16x8*)(src + r * 64 + c);
  *(bf16x8*)&T[r + 32][c] = *(const bf16x8*)(src + (r + 32) * 64 + c);
  __syncthreads();
  u16* dst = Vt + (size_t)bh * 64 * 2048 + stile * 64;
#pragma unroll
  for (int p = 0; p < 2; ++p) {
    int oc = p * 256 + tid;
    int d = oc >> 3, sc = (oc & 7) * 8;
    union { bf16x8 v; u16 e[8]; } out;
#pragma unroll
    for (int i = 0; i < 8; ++i) out.e[i] = T[sc + i][d];
    *(bf16x8*)(dst + (size_t)d * 2048 + sc) = out.v;
  }
}

// ---------------- flash attention (causal), tile-paired + split work ----------------
// WG = 512 thr = 2 groups x 4 waves. WG j handles q-tiles A=j and B=31-j
// (64 rows each). Work = (j+1)+(32-j) = 33 k-blocks, CONSTANT: flattened item
// list, group 0 -> items 0..16, group 1 -> items 17..32 (+1 dummy). Every WG
// in the grid runs exactly 17 rounds -> perfect balance. Tile A lives wholly
// in group 0 (j<=15<17): only tile B needs the cross-group merge. Each group
// double-buffers its own K/V LDS (64 KB total). Scores transposed
// (S^T = K x Q) so P^T feeds O^T = V^T x P^T from registers; exp2 domain.
__global__ __launch_bounds__(512) void attn_kernel(
    const u16* __restrict__ Qb, const u16* __restrict__ Kb,
    const u16* __restrict__ Vt, u16* __restrict__ Ob) {
  const int S = 2048;
  __shared__ u16 Kt[2][2][4096];   // [group][buf][64 keys x 64 dh]
  __shared__ u16 Vl[2][2][4096];   // [group][buf][64 dh x 64 keys]
  int tid = threadIdx.x;
  int grp = tid >> 8;
  int w = (tid >> 6) & 3;
  int lane = tid & 63;
  int ql = lane & 15, quad = lane >> 4;
  int j = blockIdx.x;              // 0..15
  int tileA = j, tileB = 31 - j;
  int bh = blockIdx.y;
  int qbaseA = tileA * 64 + w * 16;
  int qbaseB = tileB * 64 + w * 16;
  const u16* Qh = Qb + (size_t)bh * S * 64;
  const u16* Kh = Kb + (size_t)bh * S * 64;
  const u16* Vh = Vt + (size_t)bh * 64 * S;

  int r8 = lane >> 3, c8 = lane & 7;
  int swz = c8 ^ r8;
  int cb = ql & 7;
  const float SCL = 0.180336878f;  // (1/sqrt(64)) * log2(e)

  bf16x8 qA0 = *(const bf16x8*)(Qh + (size_t)(qbaseA + ql) * 64 + quad * 8);
  bf16x8 qA1 = *(const bf16x8*)(Qh + (size_t)(qbaseA + ql) * 64 + 32 + quad * 8);
  bf16x8 qB0 = *(const bf16x8*)(Qh + (size_t)(qbaseB + ql) * 64 + quad * 8);
  bf16x8 qB1 = *(const bf16x8*)(Qh + (size_t)(qbaseB + ql) * 64 + 32 + quad * 8);

  f32x4 oA[4] = {{0,0,0,0},{0,0,0,0},{0,0,0,0},{0,0,0,0}};
  f32x4 oB[4] = {{0,0,0,0},{0,0,0,0},{0,0,0,0},{0,0,0,0}};
  float mA = -3.0e38f, lA = 0.0f, mB = -3.0e38f, lB = 0.0f;

  // item i (0..32): i <= j -> (tile A, kb=i); else (tile B, kb=i-j-1)
  auto stage = [&](int buf, int kbase) {
    const u16* kg = Kh + (size_t)(kbase + w * 16 + r8) * 64 + swz * 8;
    lds_cp16(&Kt[grp][buf][w * 1024], kg);
    lds_cp16(&Kt[grp][buf][w * 1024 + 512], kg + 8 * 64);
    const u16* vg = Vh + (size_t)(w * 16 + r8) * S + kbase + swz * 8;
    lds_cp16(&Vl[grp][buf][w * 1024], vg);
    lds_cp16(&Vl[grp][buf][w * 1024 + 512], vg + 8 * S);
  };
  auto process = [&](int cur, int kbase, int qbase, bf16x8 x0, bf16x8 x1,
                     f32x4 (&o)[4], float& m, float& l) {
    int q = qbase + ql;
    f32x4 st[4];
#pragma unroll
    for (int t = 0; t < 4; ++t) {
      const u16* kr = &Kt[grp][cur][(t * 16 + ql) * 64];
      bf16x8 kf0 = *(const bf16x8*)(kr + ((quad ^ cb) * 8));
      bf16x8 kf1 = *(const bf16x8*)(kr + (((quad + 4) ^ cb) * 8));
      f32x4 s = {0, 0, 0, 0};
      s = __builtin_amdgcn_mfma_f32_16x16x32_bf16(kf0, x0, s, 0, 0, 0);
      s = __builtin_amdgcn_mfma_f32_16x16x32_bf16(kf1, x1, s, 0, 0, 0);
      st[t] = s;
    }
    bool needmask = (kbase + 63 > qbase);
    float sc[4][4];
#pragma unroll
    for (int t = 0; t < 4; ++t)
#pragma unroll
      for (int r = 0; r < 4; ++r) {
        float v = st[t][r] * SCL;
        if (needmask) {
          int key = kbase + t * 16 + quad * 4 + r;
          if (key > q) v = -3.0e38f;
        }
        sc[t][r] = v;
      }
    float mx = sc[0][0];
#pragma unroll
    for (int t = 0; t < 4; ++t)
#pragma unroll
      for (int r = 0; r < 4; ++r) mx = fmaxf(mx, sc[t][r]);
    mx = fmaxf(mx, __shfl_xor(mx, 16));
    mx = fmaxf(mx, __shfl_xor(mx, 32));
    float mn = fmaxf(m, mx);
    float alpha = fexp2(m - mn);
    m = mn;
    float rs = 0.0f;
    bf16x4 p[4];
#pragma unroll
    for (int t = 0; t < 4; ++t)
#pragma unroll
      for (int r = 0; r < 4; ++r) {
        float e = fexp2(sc[t][r] - mn);
        rs += e;
        p[t][r] = (short)f2bf(e);
      }
    rs += __shfl_xor(rs, 16);
    rs += __shfl_xor(rs, 32);
    l = l * alpha + rs;
#pragma unroll
    for (int d = 0; d < 4; ++d) o[d] *= alpha;
#pragma unroll
    for (int t = 0; t < 4; ++t)
#pragma unroll
      for (int d = 0; d < 4; ++d) {
        const u16* vr = &Vl[grp][cur][(d * 16 + ql) * 64];
        bf16x4 vf = *(const bf16x4*)(vr + (((t * 2 + (quad >> 1)) ^ cb) * 8 + (quad & 1) * 4));
        o[d] = mfma16x16x16_bf16(vf, p[t], o[d]);
      }
  };

  // prologue: stage first item of my group (always real: grp*17 <= 32)
  {
    int i0 = grp * 17;
    int kb = (i0 <= tileA) ? i0 : (i0 - tileA - 1);
    stage(0, kb * 64);
  }

  for (int r = 0; r < 17; ++r) {
    int i = grp * 17 + r;
    int cur = r & 1;
    __syncthreads();   // staging of cur drained (wave-level vmcnt(0) at barrier)
    int inext = i + 1;
    if (r + 1 < 17 && inext < 33) {
      int kb = (inext <= tileA) ? inext : (inext - tileA - 1);
      stage(cur ^ 1, kb * 64);
    }
    if (i < 33) {
      if (i <= tileA) process(cur, i * 64, qbaseA, qA0, qA1, oA, mA, lA);
      else            process(cur, (i - tileA - 1) * 64, qbaseB, qB0, qB1, oB, mB, lB);
    }
  }

  // --- epilogue. Tile A: group 0 owns it fully. Tile B: merge grp0+grp1. ---
  float* ob  = (float*)&Kt[0][0][0];   // 256 lanes x 16 floats
  float* mlb = (float*)&Vl[0][0][0];   // 256 lanes x 2 floats
  int lg = tid & 255;
  int b = bh >> 3, h = bh & 7;
  __syncthreads();
  if (grp == 1) {
#pragma unroll
    for (int d = 0; d < 4; ++d)
#pragma unroll
      for (int r = 0; r < 4; ++r) ob[lg * 16 + d * 4 + r] = oB[d][r];
    mlb[lg * 2] = mB;
    mlb[lg * 2 + 1] = lB;
  }
  __syncthreads();
  if (grp == 0) {
    // tile A (no merge)
    float invA = 1.0f / lA;
    size_t rowA = ((size_t)b * 2048 + qbaseA + ql) * 512 + h * 64;
#pragma unroll
    for (int d = 0; d < 4; ++d) {
      ushort4 v;
      v.x = f2bf(oA[d][0] * invA);
      v.y = f2bf(oA[d][1] * invA);
      v.z = f2bf(oA[d][2] * invA);
      v.w = f2bf(oA[d][3] * invA);
      *(ushort4*)(Ob + rowA + d * 16 + quad * 4) = v;
    }
    // tile B (merge with group 1 partial)
    float mBo = mlb[lg * 2], lBo = mlb[lg * 2 + 1];
    float M = fmaxf(mB, mBo);
    float a0 = fexp2(mB - M), a1 = fexp2(mBo - M);
    float L = lB * a0 + lBo * a1;
    float inv = 1.0f / L;
    size_t rowB = ((size_t)b * 2048 + qbaseB + ql) * 512 + h * 64;
#pragma unroll
    for (int d = 0; d < 4; ++d) {
      ushort4 v;
      v.x = f2bf((oB[d][0] * a0 + ob[lg * 16 + d * 4 + 0] * a1) * inv);
      v.y = f2bf((oB[d][1] * a0 + ob[lg * 16 + d * 4 + 1] * a1) * inv);
      v.z = f2bf((oB[d][2] * a0 + ob[lg * 16 + d * 4 + 2] * a1) * inv);
      v.w = f2bf((oB[d][3] * a0 + ob[lg * 16 + d * 4 + 3] * a1) * inv);
      *(ushort4*)(Ob + rowB + d * 16 + quad * 4) = v;
    }
  }
}

// ---------------- out_proj GEMM: out = O @ w_out^T + b_out (fp32 out) ----------------
__global__ __launch_bounds__(256) void outproj_gemm(
    const u16* __restrict__ Ob, const u16* __restrict__ wb,
    const float* __restrict__ bout, float* __restrict__ out) {
  const int K = 512;
  __shared__ u16 At[2][64 * 32];
  __shared__ u16 Bt[2][128 * 32];
  int tid = threadIdx.x;
  int w = tid >> 6, lane = tid & 63;
  int ql = lane & 15, quad = lane >> 4;
  int wr = w >> 1, wc = w & 1;
  int mtile = blockIdx.x * 64, ntile = blockIdx.y * 128;

  int r4 = lane >> 2, c4 = lane & 3;
  int swz4 = c4 ^ (r4 & 3);

  const u16* ag0 = Ob + (size_t)(mtile + w * 16 + r4) * K + swz4 * 8;
  const u16* bg0 = wb + (size_t)(ntile + w * 32 + r4) * K + swz4 * 8;

  f32x4 acc[2][4];
#pragma unroll
  for (int t = 0; t < 2; ++t)
#pragma unroll
    for (int u = 0; u < 4; ++u) acc[t][u] = (f32x4){0, 0, 0, 0};

  lds_cp16(&At[0][w * 512], ag0);
  lds_cp16(&Bt[0][w * 1024], bg0);
  lds_cp16(&Bt[0][w * 1024 + 512], bg0 + 16 * K);

  int cb = ql & 3;
  for (int kk = 0; kk < 16; ++kk) {
    int cur = kk & 1;
    __syncthreads();
    if (kk < 15) {
      int k0 = (kk + 1) * 32;
      lds_cp16(&At[cur ^ 1][w * 512], ag0 + k0);
      lds_cp16(&Bt[cur ^ 1][w * 1024], bg0 + k0);
      lds_cp16(&Bt[cur ^ 1][w * 1024 + 512], bg0 + 16 * K + k0);
    }
    bf16x8 af[2], bf[4];
#pragma unroll
    for (int t = 0; t < 2; ++t) {
      int row = wr * 32 + t * 16 + ql;
      af[t] = *(const bf16x8*)(&At[cur][row * 32 + ((quad ^ cb) * 8)]);
    }
#pragma unroll
    for (int u = 0; u < 4; ++u) {
      int row = wc * 64 + u * 16 + ql;
      bf[u] = *(const bf16x8*)(&Bt[cur][row * 32 + ((quad ^ cb) * 8)]);
    }
#pragma unroll
    for (int t = 0; t < 2; ++t)
#pragma unroll
      for (int u = 0; u < 4; ++u)
        acc[t][u] = __builtin_amdgcn_mfma_f32_16x16x32_bf16(af[t], bf[u], acc[t][u], 0, 0, 0);
  }

#pragma unroll
  for (int u = 0; u < 4; ++u) {
    int n = ntile + wc * 64 + u * 16 + ql;
    float bias = bout[n];
#pragma unroll
    for (int t = 0; t < 2; ++t)
#pragma unroll
      for (int r = 0; r < 4; ++r) {
        int mm = mtile + wr * 32 + t * 16 + quad * 4 + r;
        out[(size_t)mm * 512 + n] = acc[t][u][r] + bias;
      }
  }
}

extern "C" void kernel_launch(void* const* d_in, const int* in_sizes, int n_in,
                              void* d_out, int out_size, void* d_ws, size_t ws_size,
                              hipStream_t stream) {
  const float* x     = (const float*)d_in[0];  // [2,2048,512]
  const float* w_in  = (const float*)d_in[1];  // [1536,512]
  const float* b_in  = (const float*)d_in[2];  // [1536]
  const float* w_out = (const float*)d_in[3];  // [512,512]
  const float* b_out = (const float*)d_in[4];  // [512]
  float* out = (float*)d_out;                  // [2,2048,512] fp32
  char* ws = (char*)d_ws;

  u16* xb    = (u16*)(ws);             // 4096x512 bf16   (4 MB)
  u16* winb  = (u16*)(ws + 4194304);   // 1536x512 bf16   (1.5 MB)
  u16* woutb = (u16*)(ws + 5767168);   // 512x512 bf16    (0.5 MB)
  u16* Qb    = (u16*)(ws + 6291456);   // [16][2048][64]  (4 MB)
  u16* Kb    = (u16*)(ws + 10485760);  // [16][2048][64]  (4 MB)
  u16* Vt    = (u16*)(ws + 14680064);  // [16][64][2048]  (4 MB)
  u16* Ob    = (u16*)(ws + 18874368);  // [4096][512]     (4 MB)
  u16* Vrow  = Ob;   // alias: Vrow dead before attn writes Ob (stream-ordered)

  cvt_all<<<3072, 256, 0, stream>>>((const float4*)x, (const float4*)w_in,
                                    (const float4*)w_out, xb, winb, woutb);
  inproj_gemm<<<dim3(64, 12), 256, 0, stream>>>(xb, winb, b_in, Qb, Kb, Vrow);
  transpose_v<<<dim3(32, 16), 256, 0, stream>>>(Vrow, Vt);
  attn_kernel<<<dim3(16, 16), 512, 0, stream>>>(Qb, Kb, Vt, Ob);
  outproj_gemm<<<dim3(64, 4), 256, 0, stream>>>(Ob, woutb, b_out, out);
}